// Round 5
// baseline (424.188 us; speedup 1.0000x reference)
//
#include <hip/hip_runtime.h>

// ---------------------------------------------------------------------------
// Weight transpose: w[o][c][k] -> wT[(k*ci + c)*co + o]  (o contiguous so the
// compute kernel's uniform weight reads merge into s_load_dwordx4/x8).
// ---------------------------------------------------------------------------
struct WtArgs { const float* src[6]; int co[6], ci[6], k2[6], dstoff[6]; };

__global__ __launch_bounds__(256)
void transpose_weights(WtArgs a, float* __restrict__ dst0)
{
    const int L = blockIdx.x;
    const float* __restrict__ s = a.src[L];
    float* __restrict__ d = dst0 + a.dstoff[L];
    const int co = a.co[L], ci = a.ci[L], k2 = a.k2[L];
    const int n = co * ci * k2;
    for (int i = threadIdx.x; i < n; i += 256) {
        int k = i % k2;
        int c = (i / k2) % ci;
        int o = i / (k2 * ci);
        d[(k * ci + c) * co + o] = s[i];
    }
}

// ---------------------------------------------------------------------------
// Deformable conv: one block per image. Image staged in LDS channel-inner
// with padded stride S. Weights via uniform scalar loads from
// wT[(k*CIN+c)*COUT+o]. k-split across KSEG thread groups (compile-time
// KLEN with masked tail); offset loads software-pipelined one k ahead.
// x: [B][CIN][H*W]   y: [B][COUT][HO*WO]
// ---------------------------------------------------------------------------
template<int CIN, int COUT, int K, int H, int W, int HO, int WO,
         int S, int KSEG, int NT>
__global__ __launch_bounds__(NT)
void deform_lds(const float* __restrict__ x, const float* __restrict__ off,
                const float* __restrict__ wT, const float* __restrict__ bias,
                float* __restrict__ y)
{
    constexpr int K2 = K * K, HW = H * W, P = HO * WO;
    constexpr int KLEN = (K2 + KSEG - 1) / KSEG;
    constexpr int PSTR = (COUT % 2 == 0) ? COUT + 1 : COUT;   // pad partials

    __shared__ __align__(16) float simg[HW * S];
    __shared__ float part[(KSEG > 1) ? (KSEG - 1) * P * PSTR : 1];

    const int tid = threadIdx.x;
    const int b   = blockIdx.x;

    // Stage image transposed: global [c][hw] -> LDS [hw][S] (channel-inner)
    const float* xb = x + (size_t)b * CIN * HW;
    for (int i = tid; i < CIN * HW; i += NT) {
        int c = i / HW, hw = i - c * HW;
        simg[hw * S + c] = xb[i];
    }
    __syncthreads();

    const int g = tid / P;            // k-segment id (g >= KSEG -> idle)
    const int p = tid - g * P;        // output pixel

    float acc[COUT];
#pragma unroll
    for (int o = 0; o < COUT; ++o) acc[o] = 0.f;

    if (g < KSEG) {
        if (g == 0) {
#pragma unroll
            for (int o = 0; o < COUT; ++o) acc[o] = bias[o];
        }
        const int ho = p / WO, wo = p - ho * WO;
        const int kb = g * KLEN;

        // software-pipelined offset pair (prefetch distance 1, clamped)
        const int kf = (kb < K2) ? kb : (K2 - 1);
        float ndy = off[(2 * kf)     * P + p];
        float ndx = off[(2 * kf + 1) * P + p];

        auto body = [&](int j) {
            const int k  = kb + j;
            const int kk = (k < K2) ? k : (K2 - 1);
            const float dy = ndy, dx = ndx;
            // prefetch next iteration's offsets (clamped; redundant at tail)
            const int kn = (k + 1 < K2) ? (k + 1) : (K2 - 1);
            ndy = off[(2 * kn)     * P + p];
            ndx = off[(2 * kn + 1) * P + p];

            const int ky = kk / K, kx = kk - ky * K;
            const float py = (float)(ho + ky) + dy;
            const float px = (float)(wo + kx) + dx;
            const float y0f = floorf(py), x0f = floorf(px);
            const float wy = py - y0f, wx = px - x0f;
            const int y0 = (int)y0f, x0 = (int)x0f;
            const int y1 = y0 + 1,  x1 = x0 + 1;
            const bool vy0 = ((unsigned)y0 < (unsigned)H);
            const bool vy1 = ((unsigned)y1 < (unsigned)H);
            const bool vx0 = ((unsigned)x0 < (unsigned)W);
            const bool vx1 = ((unsigned)x1 < (unsigned)W);
            const int cy0 = min(max(y0, 0), H - 1) * W;
            const int cy1 = min(max(y1, 0), H - 1) * W;
            const int cx0 = min(max(x0, 0), W - 1);
            const int cx1 = min(max(x1, 0), W - 1);
            float w00 = (vy0 && vx0) ? (1.f - wy) * (1.f - wx) : 0.f;
            float w01 = (vy0 && vx1) ? (1.f - wy) * wx         : 0.f;
            float w10 = (vy1 && vx0) ? wy * (1.f - wx)         : 0.f;
            float w11 = (vy1 && vx1) ? wy * wx                 : 0.f;
            if constexpr (K2 % KSEG != 0) {
                const float kv = (k < K2) ? 1.f : 0.f;   // masked tail
                w00 *= kv; w01 *= kv; w10 *= kv; w11 *= kv;
            }

            const float* __restrict__ r00 = simg + (cy0 + cx0) * S;
            const float* __restrict__ r01 = simg + (cy0 + cx1) * S;
            const float* __restrict__ r10 = simg + (cy1 + cx0) * S;
            const float* __restrict__ r11 = simg + (cy1 + cx1) * S;
            const float* __restrict__ wk  = wT + kk * (CIN * COUT);

            if constexpr (CIN % 4 == 0) {
#pragma unroll
                for (int c4 = 0; c4 < CIN / 4; ++c4) {
                    const float4 v00 = *(const float4*)(r00 + c4 * 4);
                    const float4 v01 = *(const float4*)(r01 + c4 * 4);
                    const float4 v10 = *(const float4*)(r10 + c4 * 4);
                    const float4 v11 = *(const float4*)(r11 + c4 * 4);
                    float4 sa;
                    sa.x = fmaf(w00, v00.x, fmaf(w01, v01.x, fmaf(w10, v10.x, w11 * v11.x)));
                    sa.y = fmaf(w00, v00.y, fmaf(w01, v01.y, fmaf(w10, v10.y, w11 * v11.y)));
                    sa.z = fmaf(w00, v00.z, fmaf(w01, v01.z, fmaf(w10, v10.z, w11 * v11.z)));
                    sa.w = fmaf(w00, v00.w, fmaf(w01, v01.w, fmaf(w10, v10.w, w11 * v11.w)));
                    const float* __restrict__ wc = wk + (c4 * 4) * COUT;
#pragma unroll
                    for (int o = 0; o < COUT; ++o) acc[o] = fmaf(wc[o], sa.x, acc[o]);
#pragma unroll
                    for (int o = 0; o < COUT; ++o) acc[o] = fmaf(wc[COUT + o], sa.y, acc[o]);
#pragma unroll
                    for (int o = 0; o < COUT; ++o) acc[o] = fmaf(wc[2 * COUT + o], sa.z, acc[o]);
#pragma unroll
                    for (int o = 0; o < COUT; ++o) acc[o] = fmaf(wc[3 * COUT + o], sa.w, acc[o]);
                }
            } else {
#pragma unroll
                for (int c = 0; c < CIN; ++c) {
                    float sa = fmaf(w00, r00[c], fmaf(w01, r01[c],
                               fmaf(w10, r10[c], w11 * r11[c])));
#pragma unroll
                    for (int o = 0; o < COUT; ++o)
                        acc[o] = fmaf(wk[c * COUT + o], sa, acc[o]);
                }
            }
        };

        if constexpr (CIN == 1) {
#pragma unroll
            for (int j = 0; j < KLEN; ++j) body(j);
        } else {
#pragma unroll 1
            for (int j = 0; j < KLEN; ++j) body(j);
        }

        if (g > 0) {
#pragma unroll
            for (int o = 0; o < COUT; ++o)
                part[(g - 1) * (P * PSTR) + p * PSTR + o] = acc[o];
        }
    }

    if constexpr (KSEG > 1) __syncthreads();

    if (g == 0) {
        if constexpr (KSEG > 1) {
#pragma unroll
            for (int gg = 1; gg < KSEG; ++gg)
#pragma unroll
                for (int o = 0; o < COUT; ++o)
                    acc[o] += part[(gg - 1) * (P * PSTR) + p * PSTR + o];
        }
        float* yb = y + (size_t)b * COUT * P;
#pragma unroll
        for (int o = 0; o < COUT; ++o)
            yb[o * P + p] = fmaxf(acc[o], 0.f);
    }
}

// ---------------------------------------------------------------------------
// Fused head: perm gather + FC(676->256) + ReLU + FC(256->10).
// 64 blocks x 256 threads; each block handles 4 batch rows.
// ---------------------------------------------------------------------------
__global__ __launch_bounds__(256)
void fc_head(const float* __restrict__ x6, const float* __restrict__ w7,
             const float* __restrict__ b7, const float* __restrict__ w8,
             const float* __restrict__ b8, const int* __restrict__ perm,
             float* __restrict__ out)
{
    constexpr int BPB = 4;
    constexpr int F   = 676;
    __shared__ float sx[BPB][F];
    __shared__ float sh[BPB][256];

    const int tid = threadIdx.x;
    const int b0  = blockIdx.x * BPB;

    for (int i = tid; i < BPB * F; i += 256) {
        int bb = i / F, f = i - bb * F;
        int c = f / 169, p = f - c * 169;
        sx[bb][f] = x6[(size_t)(b0 + bb) * F + c * 169 + perm[p]];
    }
    __syncthreads();

    float acc[BPB];
#pragma unroll
    for (int bb = 0; bb < BPB; ++bb) acc[bb] = b7[tid];
#pragma unroll 4
    for (int i = 0; i < F; ++i) {
        const float wv = w7[i * 256 + tid];
#pragma unroll
        for (int bb = 0; bb < BPB; ++bb)
            acc[bb] = fmaf(sx[bb][i], wv, acc[bb]);
    }
#pragma unroll
    for (int bb = 0; bb < BPB; ++bb) sh[bb][tid] = fmaxf(acc[bb], 0.f);
    __syncthreads();

    if (tid < BPB * 10) {
        int bb = tid / 10, t = tid - bb * 10;
        float a = b8[t];
#pragma unroll 8
        for (int j = 0; j < 256; ++j)
            a = fmaf(sh[bb][j], w8[j * 10 + t], a);
        out[(size_t)(b0 + bb) * 10 + t] = a;
    }
}

// ---------------------------------------------------------------------------
extern "C" void kernel_launch(void* const* d_in, const int* in_sizes, int n_in,
                              void* d_out, int out_size, void* d_ws, size_t ws_size,
                              hipStream_t stream)
{
    const float* x    = (const float*)d_in[0];
    const float* off1 = (const float*)d_in[1];
    const float* w1   = (const float*)d_in[2];
    const float* b1   = (const float*)d_in[3];
    const float* off2 = (const float*)d_in[4];
    const float* w2   = (const float*)d_in[5];
    const float* b2   = (const float*)d_in[6];
    const float* off3 = (const float*)d_in[7];
    const float* w3   = (const float*)d_in[8];
    const float* b3   = (const float*)d_in[9];
    const float* off4 = (const float*)d_in[10];
    const float* w4   = (const float*)d_in[11];
    const float* b4   = (const float*)d_in[12];
    const float* off5 = (const float*)d_in[13];
    const float* w5   = (const float*)d_in[14];
    const float* b5   = (const float*)d_in[15];
    const float* off6 = (const float*)d_in[16];
    const float* w6   = (const float*)d_in[17];
    const float* b6   = (const float*)d_in[18];
    const float* w7   = (const float*)d_in[19];
    const float* b7   = (const float*)d_in[20];
    const float* w8   = (const float*)d_in[21];
    const float* b8   = (const float*)d_in[22];
    const int*   perm = (const int*)d_in[23];
    float* out = (float*)d_out;

    // ws layout (floats), identical footprint to the proven layout:
    // wt @0 (33,792), buf0 @33,792 (3,936,256), buf1 after (6,889,472)
    const int woff[6] = {0, 144, 4752, 17552, 30096, 33296};
    float* ws   = (float*)d_ws;
    float* wt   = ws;
    float* buf0 = ws + 33792;
    float* buf1 = buf0 + 3936256;

    float* a1 = buf0;   // 256*16*961
    float* a2 = buf1;   // 256*32*841
    float* a3 = buf0;   // 256*16*625
    float* a4 = buf1;   // 256*16*361
    float* a5 = buf0;   // 256*8*225
    float* a6 = buf1;   // 256*4*169

    WtArgs wa;
    wa.src[0] = w1; wa.src[1] = w2; wa.src[2] = w3;
    wa.src[3] = w4; wa.src[4] = w5; wa.src[5] = w6;
    const int cos[6] = {16, 32, 16, 16, 8, 4};
    const int cis[6] = {1, 16, 32, 16, 16, 8};
    const int k2s[6] = {9, 9, 25, 49, 25, 9};
    for (int i = 0; i < 6; ++i) {
        wa.co[i] = cos[i]; wa.ci[i] = cis[i];
        wa.k2[i] = k2s[i]; wa.dstoff[i] = woff[i];
    }
    transpose_weights<<<dim3(6), dim3(256), 0, stream>>>(wa, wt);

    const dim3 grid(256);
    // <CIN,COUT,K,H,W,HO,WO,S,KSEG,NT>
    deform_lds< 1, 16, 3, 33, 33, 31, 31,  1, 1, 1024><<<grid, dim3(1024), 0, stream>>>(x,  off1, wt + woff[0], b1, a1);
    deform_lds<16, 32, 3, 31, 31, 29, 29, 20, 1, 1024><<<grid, dim3(1024), 0, stream>>>(a1, off2, wt + woff[1], b2, a2);
    deform_lds<32, 16, 5, 29, 29, 25, 25, 36, 1, 1024><<<grid, dim3(1024), 0, stream>>>(a2, off3, wt + woff[2], b3, a3);
    deform_lds<16, 16, 7, 25, 25, 19, 19, 20, 2,  768><<<grid, dim3(768),  0, stream>>>(a3, off4, wt + woff[3], b4, a4);
    deform_lds<16,  8, 5, 19, 19, 15, 15, 20, 4, 1024><<<grid, dim3(1024), 0, stream>>>(a4, off5, wt + woff[4], b5, a5);
    deform_lds< 8,  4, 3, 15, 15, 13, 13, 12, 3,  512><<<grid, dim3(512),  0, stream>>>(a5, off6, wt + woff[5], b6, a6);

    fc_head<<<dim3(64), dim3(256), 0, stream>>>(a6, w7, b7, w8, b8, perm, out);
}

// Round 6
// 315.767 us; speedup vs baseline: 1.3434x; 1.3434x over previous
//
#include <hip/hip_runtime.h>

// ---------------------------------------------------------------------------
// Weight transpose: w[o][c][k] -> wT[(k*ci + c)*co + o]  (o contiguous so the
// compute kernel's uniform weight reads merge into s_load_dwordx4/x8).
// ---------------------------------------------------------------------------
struct WtArgs { const float* src[6]; int co[6], ci[6], k2[6], dstoff[6]; };

__global__ __launch_bounds__(256)
void transpose_weights(WtArgs a, float* __restrict__ dst0)
{
    const int L = blockIdx.x;
    const float* __restrict__ s = a.src[L];
    float* __restrict__ d = dst0 + a.dstoff[L];
    const int co = a.co[L], ci = a.ci[L], k2 = a.k2[L];
    const int n = co * ci * k2;
    for (int i = threadIdx.x; i < n; i += 256) {
        int k = i % k2;
        int c = (i / k2) % ci;
        int o = i / (k2 * ci);
        d[(k * ci + c) * co + o] = s[i];
    }
}

// ---------------------------------------------------------------------------
// Deformable conv: one block per image. Image staged in LDS channel-inner
// with padded stride S. k-split across KSEG WAVE-ALIGNED thread groups
// (PW = ceil(P/64)*64), so the group id g and the weight index kk are
// wave-uniform; readfirstlane(kk) forces the weight base into SGPRs ->
// s_load_dwordx8/16 weight streams (no per-lane vector weight loads).
// x: [B][CIN][H*W]   y: [B][COUT][HO*WO]
// ---------------------------------------------------------------------------
template<int CIN, int COUT, int K, int H, int W, int HO, int WO,
         int S, int KSEG, int NT>
__global__ __launch_bounds__(NT)
void deform_lds(const float* __restrict__ x, const float* __restrict__ off,
                const float* __restrict__ wT, const float* __restrict__ bias,
                float* __restrict__ y)
{
    constexpr int K2 = K * K, HW = H * W, P = HO * WO;
    constexpr int PW = ((P + 63) / 64) * 64;              // wave-aligned group
    constexpr int KLEN = (K2 + KSEG - 1) / KSEG;
    constexpr int PSTR = (COUT % 2 == 0) ? COUT + 1 : COUT;
    static_assert(NT >= KSEG * PW, "NT too small for KSEG*PW");

    __shared__ __align__(16) float simg[HW * S];
    __shared__ float part[(KSEG > 1) ? (KSEG - 1) * P * PSTR : 1];

    const int tid = threadIdx.x;
    const int b   = blockIdx.x;

    // Stage image transposed: global [c][hw] -> LDS [hw][S] (channel-inner)
    const float* xb = x + (size_t)b * CIN * HW;
    for (int i = tid; i < CIN * HW; i += NT) {
        int c = i / HW, hw = i - c * HW;
        simg[hw * S + c] = xb[i];
    }
    __syncthreads();

    const int g  = tid / PW;              // wave-uniform group id
    const int p  = tid - g * PW;          // output pixel (may be >= P)
    const int pc = (p < P) ? p : (P - 1); // clamped for loads
    const bool active = (p < P);

    float acc[COUT];
#pragma unroll
    for (int o = 0; o < COUT; ++o) acc[o] = 0.f;

    if (g < KSEG) {
        if (g == 0) {
#pragma unroll
            for (int o = 0; o < COUT; ++o) acc[o] = bias[o];
        }
        const int ho = pc / WO, wo = pc - ho * WO;
        const int kb = g * KLEN;

        // software-pipelined offset pair (prefetch distance 1, clamped)
        const int kf = (kb < K2) ? kb : (K2 - 1);
        float ndy = off[(2 * kf)     * P + pc];
        float ndx = off[(2 * kf + 1) * P + pc];

#pragma unroll 1
        for (int j = 0; j < KLEN; ++j) {
            const int k  = kb + j;                    // wave-uniform
            const int kk = (k < K2) ? k : (K2 - 1);   // wave-uniform clamp
            const float dy = ndy, dx = ndx;
            const int kn = (k + 1 < K2) ? (k + 1) : (K2 - 1);
            ndy = off[(2 * kn)     * P + pc];
            ndx = off[(2 * kn + 1) * P + pc];

            const int ky = kk / K, kx = kk - ky * K;
            const float py = (float)(ho + ky) + dy;
            const float px = (float)(wo + kx) + dx;
            const float y0f = floorf(py), x0f = floorf(px);
            const float wy = py - y0f, wx = px - x0f;
            const int y0 = (int)y0f, x0 = (int)x0f;
            const int y1 = y0 + 1,  x1 = x0 + 1;
            const bool vy0 = ((unsigned)y0 < (unsigned)H);
            const bool vy1 = ((unsigned)y1 < (unsigned)H);
            const bool vx0 = ((unsigned)x0 < (unsigned)W);
            const bool vx1 = ((unsigned)x1 < (unsigned)W);
            const int cy0 = min(max(y0, 0), H - 1) * W;
            const int cy1 = min(max(y1, 0), H - 1) * W;
            const int cx0 = min(max(x0, 0), W - 1);
            const int cx1 = min(max(x1, 0), W - 1);
            float w00 = (vy0 && vx0) ? (1.f - wy) * (1.f - wx) : 0.f;
            float w01 = (vy0 && vx1) ? (1.f - wy) * wx         : 0.f;
            float w10 = (vy1 && vx0) ? wy * (1.f - wx)         : 0.f;
            float w11 = (vy1 && vx1) ? wy * wx                 : 0.f;
            if constexpr (K2 % KSEG != 0) {
                const float kv = (k < K2) ? 1.f : 0.f;   // masked tail (uniform)
                w00 *= kv; w01 *= kv; w10 *= kv; w11 *= kv;
            }

            const float* __restrict__ r00 = simg + (cy0 + cx0) * S;
            const float* __restrict__ r01 = simg + (cy0 + cx1) * S;
            const float* __restrict__ r10 = simg + (cy1 + cx0) * S;
            const float* __restrict__ r11 = simg + (cy1 + cx1) * S;
            // force SGPR weight base (kk is wave-uniform by construction)
            const int kku = __builtin_amdgcn_readfirstlane(kk);
            const float* __restrict__ wk = wT + kku * (CIN * COUT);

            if constexpr (CIN % 4 == 0) {
#pragma unroll
                for (int c4 = 0; c4 < CIN / 4; ++c4) {
                    const float4 v00 = *(const float4*)(r00 + c4 * 4);
                    const float4 v01 = *(const float4*)(r01 + c4 * 4);
                    const float4 v10 = *(const float4*)(r10 + c4 * 4);
                    const float4 v11 = *(const float4*)(r11 + c4 * 4);
                    float4 sa;
                    sa.x = fmaf(w00, v00.x, fmaf(w01, v01.x, fmaf(w10, v10.x, w11 * v11.x)));
                    sa.y = fmaf(w00, v00.y, fmaf(w01, v01.y, fmaf(w10, v10.y, w11 * v11.y)));
                    sa.z = fmaf(w00, v00.z, fmaf(w01, v01.z, fmaf(w10, v10.z, w11 * v11.z)));
                    sa.w = fmaf(w00, v00.w, fmaf(w01, v01.w, fmaf(w10, v10.w, w11 * v11.w)));
                    const float* __restrict__ wc = wk + (c4 * 4) * COUT;
#pragma unroll
                    for (int o = 0; o < COUT; ++o) acc[o] = fmaf(wc[o], sa.x, acc[o]);
#pragma unroll
                    for (int o = 0; o < COUT; ++o) acc[o] = fmaf(wc[COUT + o], sa.y, acc[o]);
#pragma unroll
                    for (int o = 0; o < COUT; ++o) acc[o] = fmaf(wc[2 * COUT + o], sa.z, acc[o]);
#pragma unroll
                    for (int o = 0; o < COUT; ++o) acc[o] = fmaf(wc[3 * COUT + o], sa.w, acc[o]);
                }
            } else {
#pragma unroll
                for (int c = 0; c < CIN; ++c) {
                    float sa = fmaf(w00, r00[c], fmaf(w01, r01[c],
                               fmaf(w10, r10[c], w11 * r11[c])));
#pragma unroll
                    for (int o = 0; o < COUT; ++o)
                        acc[o] = fmaf(wk[c * COUT + o], sa, acc[o]);
                }
            }
        }

        if (g > 0 && active) {
#pragma unroll
            for (int o = 0; o < COUT; ++o)
                part[(g - 1) * (P * PSTR) + p * PSTR + o] = acc[o];
        }
    }

    if constexpr (KSEG > 1) __syncthreads();

    if (g == 0 && active) {
        if constexpr (KSEG > 1) {
#pragma unroll
            for (int gg = 1; gg < KSEG; ++gg)
#pragma unroll
                for (int o = 0; o < COUT; ++o)
                    acc[o] += part[(gg - 1) * (P * PSTR) + p * PSTR + o];
        }
        float* yb = y + (size_t)b * COUT * P;
#pragma unroll
        for (int o = 0; o < COUT; ++o)
            yb[o * P + p] = fmaxf(acc[o], 0.f);
    }
}

// ---------------------------------------------------------------------------
// Fused head: perm gather + FC(676->256) + ReLU + FC(256->10).
// 64 blocks x 256 threads; each block handles 4 batch rows.
// ---------------------------------------------------------------------------
__global__ __launch_bounds__(256)
void fc_head(const float* __restrict__ x6, const float* __restrict__ w7,
             const float* __restrict__ b7, const float* __restrict__ w8,
             const float* __restrict__ b8, const int* __restrict__ perm,
             float* __restrict__ out)
{
    constexpr int BPB = 4;
    constexpr int F   = 676;
    __shared__ float sx[BPB][F];
    __shared__ float sh[BPB][256];

    const int tid = threadIdx.x;
    const int b0  = blockIdx.x * BPB;

    for (int i = tid; i < BPB * F; i += 256) {
        int bb = i / F, f = i - bb * F;
        int c = f / 169, p = f - c * 169;
        sx[bb][f] = x6[(size_t)(b0 + bb) * F + c * 169 + perm[p]];
    }
    __syncthreads();

    float acc[BPB];
#pragma unroll
    for (int bb = 0; bb < BPB; ++bb) acc[bb] = b7[tid];
#pragma unroll 4
    for (int i = 0; i < F; ++i) {
        const float wv = w7[i * 256 + tid];
#pragma unroll
        for (int bb = 0; bb < BPB; ++bb)
            acc[bb] = fmaf(sx[bb][i], wv, acc[bb]);
    }
#pragma unroll
    for (int bb = 0; bb < BPB; ++bb) sh[bb][tid] = fmaxf(acc[bb], 0.f);
    __syncthreads();

    if (tid < BPB * 10) {
        int bb = tid / 10, t = tid - bb * 10;
        float a = b8[t];
#pragma unroll 8
        for (int j = 0; j < 256; ++j)
            a = fmaf(sh[bb][j], w8[j * 10 + t], a);
        out[(size_t)(b0 + bb) * 10 + t] = a;
    }
}

// ---------------------------------------------------------------------------
extern "C" void kernel_launch(void* const* d_in, const int* in_sizes, int n_in,
                              void* d_out, int out_size, void* d_ws, size_t ws_size,
                              hipStream_t stream)
{
    const float* x    = (const float*)d_in[0];
    const float* off1 = (const float*)d_in[1];
    const float* w1   = (const float*)d_in[2];
    const float* b1   = (const float*)d_in[3];
    const float* off2 = (const float*)d_in[4];
    const float* w2   = (const float*)d_in[5];
    const float* b2   = (const float*)d_in[6];
    const float* off3 = (const float*)d_in[7];
    const float* w3   = (const float*)d_in[8];
    const float* b3   = (const float*)d_in[9];
    const float* off4 = (const float*)d_in[10];
    const float* w4   = (const float*)d_in[11];
    const float* b4   = (const float*)d_in[12];
    const float* off5 = (const float*)d_in[13];
    const float* w5   = (const float*)d_in[14];
    const float* b5   = (const float*)d_in[15];
    const float* off6 = (const float*)d_in[16];
    const float* w6   = (const float*)d_in[17];
    const float* b6   = (const float*)d_in[18];
    const float* w7   = (const float*)d_in[19];
    const float* b7   = (const float*)d_in[20];
    const float* w8   = (const float*)d_in[21];
    const float* b8   = (const float*)d_in[22];
    const int*   perm = (const int*)d_in[23];
    float* out = (float*)d_out;

    // ws layout (floats), identical footprint to the proven layout:
    // wt @0 (33,792), buf0 @33,792 (3,936,256), buf1 after (6,889,472)
    const int woff[6] = {0, 144, 4752, 17552, 30096, 33296};
    float* ws   = (float*)d_ws;
    float* wt   = ws;
    float* buf0 = ws + 33792;
    float* buf1 = buf0 + 3936256;

    float* a1 = buf0;   // 256*16*961
    float* a2 = buf1;   // 256*32*841
    float* a3 = buf0;   // 256*16*625
    float* a4 = buf1;   // 256*16*361
    float* a5 = buf0;   // 256*8*225
    float* a6 = buf1;   // 256*4*169

    WtArgs wa;
    wa.src[0] = w1; wa.src[1] = w2; wa.src[2] = w3;
    wa.src[3] = w4; wa.src[4] = w5; wa.src[5] = w6;
    const int cos[6] = {16, 32, 16, 16, 8, 4};
    const int cis[6] = {1, 16, 32, 16, 16, 8};
    const int k2s[6] = {9, 9, 25, 49, 25, 9};
    for (int i = 0; i < 6; ++i) {
        wa.co[i] = cos[i]; wa.ci[i] = cis[i];
        wa.k2[i] = k2s[i]; wa.dstoff[i] = woff[i];
    }
    transpose_weights<<<dim3(6), dim3(256), 0, stream>>>(wa, wt);

    const dim3 grid(256);
    // <CIN,COUT,K,H,W,HO,WO,S,KSEG,NT>   (PW: L1 1024, L2 896, L3 640,
    //  L4 384, L5 256, L6 192 — all wave-aligned k-groups)
    deform_lds< 1, 16, 3, 33, 33, 31, 31,  1, 1, 1024><<<grid, dim3(1024), 0, stream>>>(x,  off1, wt + woff[0], b1, a1);
    deform_lds<16, 32, 3, 31, 31, 29, 29, 20, 1, 1024><<<grid, dim3(1024), 0, stream>>>(a1, off2, wt + woff[1], b2, a2);
    deform_lds<32, 16, 5, 29, 29, 25, 25, 36, 1, 1024><<<grid, dim3(1024), 0, stream>>>(a2, off3, wt + woff[2], b3, a3);
    deform_lds<16, 16, 7, 25, 25, 19, 19, 20, 2,  768><<<grid, dim3(768),  0, stream>>>(a3, off4, wt + woff[3], b4, a4);
    deform_lds<16,  8, 5, 19, 19, 15, 15, 20, 4, 1024><<<grid, dim3(1024), 0, stream>>>(a4, off5, wt + woff[4], b5, a5);
    deform_lds< 8,  4, 3, 15, 15, 13, 13, 12, 5,  960><<<grid, dim3(960),  0, stream>>>(a5, off6, wt + woff[5], b6, a6);

    fc_head<<<dim3(64), dim3(256), 0, stream>>>(a6, w7, b7, w8, b8, perm, out);
}